// Round 3
// baseline (4209.614 us; speedup 1.0000x reference)
//
#include <hip/hip_runtime.h>

typedef unsigned short u16;
typedef __bf16 bf16x8 __attribute__((ext_vector_type(8)));
typedef float f32x4 __attribute__((ext_vector_type(4)));

#define T_STEPS 8
#define KT_COUNT 144        // K=4608 per half, BK=32

__device__ __forceinline__ u16 f2bf(float f) {
    unsigned u = __float_as_uint(f);
    return (u16)((u + 0x7fff + ((u >> 16) & 1)) >> 16);
}
__device__ __forceinline__ float sigmoidf(float x) {
    return 1.f / (1.f + expf(-x));
}

// Async global->LDS 16B DMA. LDS dst = wave-uniform base + lane*16.
__device__ __forceinline__ void async16(const void* g, void* l) {
    __builtin_amdgcn_global_load_lds(
        (const __attribute__((address_space(1))) void*)(unsigned long long)g,
        (__attribute__((address_space(3))) void*)(unsigned int)(unsigned long long)l,
        16, 0, 0);
}

// ---------------------------------------------------------------------------
// Repack conv_w fp32 [2048][1024][3][3] -> bf16 [co_blk][kt(144)][quad][128][8]
// (k' = r*512 + ci). Thread reads 9 contiguous floats (one (co,ci), all taps):
// fully coalesced 36B-stride reads across lanes.
// ---------------------------------------------------------------------------
__global__ __launch_bounds__(256) void repack_w(const float* __restrict__ w,
                                                u16* __restrict__ wx,
                                                u16* __restrict__ wh) {
    int g = blockIdx.x * 256 + threadIdx.x;   // 2 * 2048 * 512 = 2,097,152
    int ci = g & 511;
    int co = (g >> 9) & 2047;
    int part = g >> 20;
    const float* src = w + ((size_t)co * 1024 + part * 512 + ci) * 9;
    u16* dst = part ? wh : wx;
    int co_blk = co >> 7, co_in = co & 127;
    int quad = (ci >> 3) & 3, j = ci & 7;
    int kt_base = ci >> 5;
#pragma unroll
    for (int r = 0; r < 9; r++) {
        int kt = r * 16 + kt_base;
        dst[((((size_t)co_blk * 144 + kt) * 4 + quad) * 128 + co_in) * 8 + j] =
            f2bf(src[r]);
    }
}

// ---------------------------------------------------------------------------
// Layer-0 input: x fp32 [2][512][8][32][32] -> padded channel-last bf16
// P [(b*8+t)][34][34][512] (interior only; borders pre-zeroed).
// ---------------------------------------------------------------------------
__global__ __launch_bounds__(256) void transpose_x(const float* __restrict__ x,
                                                   u16* __restrict__ Px) {
    __shared__ u16 tile[32][514];
    int bid = blockIdx.x;                 // 2*8*32 = 512: (b, t, y)
    int b = bid >> 8, t = (bid >> 5) & 7, y = bid & 31;
    for (int it = 0; it < 64; ++it) {
        int idx = it * 256 + threadIdx.x;
        int xx = idx & 31, ci = idx >> 5;
        tile[xx][ci] = f2bf(x[(((size_t)(b * 512 + ci)) * 8 + t) * 1024 + y * 32 + xx]);
    }
    __syncthreads();
    u16* base = Px + ((((size_t)b * 8 + t) * 34 + y + 1) * 34 + 1) * 512;
    for (int it = 0; it < 64; ++it) {
        int idx = it * 256 + threadIdx.x;
        int ci = idx & 511, xx = idx >> 9;
        base[(size_t)xx * 512 + ci] = tile[xx][ci];
    }
}

__global__ void zero_u16(u16* __restrict__ p, int n) {
    int i = blockIdx.x * 256 + threadIdx.x;
    if (i < n) p[i] = 0;
}

// ---------------------------------------------------------------------------
// Implicit-im2col conv GEMM, m97 structure: 128 x TN tile, BK=32, 256 threads
// = 4 waves, each wave 64 x (TN/2), 16x16x32 bf16 MFMA, global_load_lds 16B.
// P: padded channel-last acts [(b*8+t)][34][34][512] bf16, zero halo ->
// no boundary predication; B fragment = 1 contiguous 16B load.
// two_t: n covers 2 timesteps x 2 batch (plane=n>>10: b=plane&1, t=t0+plane/2)
// else  : n covers batch only (b=n>>10, t=t0).
// ---------------------------------------------------------------------------
template<int TN>
__global__ __launch_bounds__(256) void conv_gemm(
    const u16* __restrict__ W, const u16* __restrict__ P,
    float* __restrict__ Z, int ldz, int t0, int two_t) {

    constexpr int BITER = (TN * 4) / 256;           // B 16B slots per thread
    __shared__ __align__(16) u16 As[4][128][8];     // 8 KB
    __shared__ __align__(16) u16 Bs[4][TN][8];      // 8 or 4 KB

    const int tid = threadIdx.x;
    const int wave = tid >> 6, lane = tid & 63;
    const int q_l = lane >> 4, m_l = lane & 15;
    const int co_blk = blockIdx.y;
    const int n0 = blockIdx.x * TN;
    const int wm = wave >> 1, wn = wave & 1;

    // Per-slot global base pointers for B
    const u16* pbb[BITER ? BITER : 1];
#pragma unroll
    for (int i = 0; i < BITER; i++) {
        int slot = i * 256 + tid;
        int quad = slot / TN;
        int row  = slot % TN;
        int n_g = n0 + row;
        int b, t;
        if (two_t) { int plane = n_g >> 10; b = plane & 1; t = t0 + (plane >> 1); }
        else       { b = n_g >> 10; t = t0; }
        int s = n_g & 1023;
        int py = s >> 5, px = s & 31;
        pbb[i] = P + ((((size_t)b * 8 + t) * 34 + py + 1) * 34 + (px + 1)) * 512
               + quad * 8;
    }

    const u16* Wco = W + (size_t)co_blk * (KT_COUNT * 4096);
    u16* ldsA0 = &As[0][0][0] + ((size_t)wave * 64) * 8;
    u16* ldsA1 = &As[0][0][0] + ((size_t)(256 + wave * 64)) * 8;
    u16* ldsB0 = &Bs[0][0][0] + ((size_t)wave * 64) * 8;
    u16* ldsB1 = &Bs[0][0][0] + ((size_t)(256 + wave * 64)) * 8;

    f32x4 acc[4][TN / 32];
#pragma unroll
    for (int i = 0; i < 4; i++)
#pragma unroll
        for (int j = 0; j < TN / 32; j++) acc[i][j] = (f32x4){0.f, 0.f, 0.f, 0.f};

    for (int kt = 0; kt < KT_COUNT; ++kt) {
        const int r = kt >> 4;
        const int ci0 = (kt & 15) * 32;
        const int doff = ((r / 3 - 1) * 34 + (r % 3 - 1)) * 512 + ci0;
        const u16* ga = Wco + (size_t)kt * 4096 + tid * 8;

        __syncthreads();   // prior iter's fragment reads complete
        async16(ga, ldsA0);
        async16(ga + 2048, ldsA1);
        async16(pbb[0] + doff, ldsB0);
        if (BITER == 2) async16(pbb[1] + doff, ldsB1);
        __syncthreads();   // DMA complete (vmcnt drain) + visible

        bf16x8 af[4], bfr[TN / 32];
#pragma unroll
        for (int mt = 0; mt < 4; mt++)
            af[mt] = *(const bf16x8*)&As[q_l][wm * 64 + mt * 16 + m_l][0];
#pragma unroll
        for (int nt = 0; nt < TN / 32; nt++)
            bfr[nt] = *(const bf16x8*)&Bs[q_l][wn * (TN / 2) + nt * 16 + m_l][0];
#pragma unroll
        for (int mt = 0; mt < 4; mt++)
#pragma unroll
            for (int nt = 0; nt < TN / 32; nt++)
                acc[mt][nt] = __builtin_amdgcn_mfma_f32_16x16x32_bf16(
                    af[mt], bfr[nt], acc[mt][nt], 0, 0, 0);
    }

    // C/D layout: col = lane&15 (n), row = (lane>>4)*4 + reg (m)
#pragma unroll
    for (int mt = 0; mt < 4; mt++)
#pragma unroll
        for (int nt = 0; nt < TN / 32; nt++)
#pragma unroll
            for (int reg = 0; reg < 4; reg++) {
                int co = co_blk * 128 + wm * 64 + mt * 16 + q_l * 4 + reg;
                int n  = n0 + wn * (TN / 2) + nt * 16 + m_l;
                Z[(size_t)co * ldz + n] = acc[mt][nt][reg];
            }
}

// ---------------------------------------------------------------------------
// Gates: fp32 math; block = (b, co0:64, s0:64); reads s-coalesced; H written
// to padded channel-last Pout via LDS transpose (co-coalesced).
// ---------------------------------------------------------------------------
__global__ __launch_bounds__(256) void gates_kernel(
    const float* __restrict__ zx, int nxbase,
    const float* __restrict__ zh,
    const float* __restrict__ bias,
    const float* __restrict__ wci, const float* __restrict__ wcf,
    const float* __restrict__ wco,
    float* __restrict__ C, int has_h,
    u16* __restrict__ Pout, int t,
    float* __restrict__ outp) {
    __shared__ u16 Ht[64][66];
    int bid = blockIdx.x;                 // 2 * 8 * 16 = 256
    int b = bid >> 7;
    int co0 = ((bid >> 4) & 7) * 64;
    int s0 = (bid & 15) * 64;
    for (int it = 0; it < 16; ++it) {
        int idx = it * 256 + threadIdx.x;
        int s_l = idx & 63, co_l = idx >> 6;
        int co = co0 + co_l, s = s0 + s_l;
        size_t nx = nxbase + b * 1024 + s;
        float zi = zx[(size_t)co * 4096 + nx]          + bias[co];
        float zf = zx[(size_t)(co + 512) * 4096 + nx]  + bias[co + 512];
        float zc = zx[(size_t)(co + 1024) * 4096 + nx] + bias[co + 1024];
        float zo = zx[(size_t)(co + 1536) * 4096 + nx] + bias[co + 1536];
        float Cp = 0.f;
        int cidx = (b * 512 + co) * 1024 + s;
        if (has_h) {
            size_t nh = b * 1024 + s;
            zi += zh[(size_t)co * 2048 + nh];
            zf += zh[(size_t)(co + 512) * 2048 + nh];
            zc += zh[(size_t)(co + 1024) * 2048 + nh];
            zo += zh[(size_t)(co + 1536) * 2048 + nh];
            Cp = C[cidx];
        }
        int ps = co * 1024 + s;
        float gi = sigmoidf(zi + wci[ps] * Cp);
        float gf = sigmoidf(zf + wcf[ps] * Cp);
        float Cn = gf * Cp + gi * fmaxf(zc, 0.f);
        float go = sigmoidf(zo + wco[ps] * Cn);
        float Hn = go * fmaxf(Cn, 0.f);
        C[cidx] = Cn;
        Ht[co_l][s_l] = f2bf(Hn);
        if (outp) outp[cidx] = sigmoidf(Hn);
    }
    __syncthreads();
    for (int it = 0; it < 16; ++it) {
        int idx = it * 256 + threadIdx.x;
        int co_l = idx & 63, s_l = idx >> 6;
        int s = s0 + s_l;
        int py = s >> 5, px = s & 31;
        Pout[((((size_t)b * 8 + t) * 34 + py + 1) * 34 + (px + 1)) * 512
             + co0 + co_l] = Ht[co_l][s_l];
    }
}

// ---------------------------------------------------------------------------
extern "C" void kernel_launch(void* const* d_in, const int* in_sizes, int n_in,
                              void* d_out, int out_size, void* d_ws, size_t ws_size,
                              hipStream_t stream) {
    const float* x = (const float*)d_in[0];

    char* ws = (char*)d_ws;
    size_t off = 0;
    auto carve = [&](size_t bytes) { char* p = ws + off; off += (bytes + 255) & ~(size_t)255; return p; };

    u16*   Wx   = (u16*)  carve((size_t)16 * KT_COUNT * 4096 * 2);   // 18.87 MB
    u16*   Wh   = (u16*)  carve((size_t)16 * KT_COUNT * 4096 * 2);   // 18.87 MB
    u16*   PxB  = (u16*)  carve((size_t)16 * 34 * 34 * 512 * 2);     // 18.94 MB
    u16*   PaB  = (u16*)  carve((size_t)16 * 34 * 34 * 512 * 2);     // 18.94 MB
    float* Zx   = (float*)carve((size_t)2048 * 4096 * 4);            // 33.55 MB
    float* Zh   = (float*)carve((size_t)2048 * 2048 * 4);            // 16.78 MB
    float* Cbuf = (float*)carve((size_t)2 * 512 * 1024 * 4);         //  4.19 MB
    (void)ws_size; (void)in_sizes; (void)n_in; (void)out_size;       // ~130.2 MB

    const size_t PBYTES = (size_t)16 * 34 * 34 * 512 * 2;
    hipMemsetAsync(PxB, 0, PBYTES, stream);
    hipMemsetAsync(PaB, 0, PBYTES, stream);

    for (int l = 0; l < 3; ++l) {
        const float* w    = (const float*)d_in[1 + 5 * l];
        const float* bias = (const float*)d_in[2 + 5 * l];
        const float* wci  = (const float*)d_in[3 + 5 * l];
        const float* wcf  = (const float*)d_in[4 + 5 * l];
        const float* wco  = (const float*)d_in[5 + 5 * l];
        // l0: Px -> Pa, l1: Pa -> Px, l2: Px -> Pa
        u16* Pin  = (l == 1) ? PaB : PxB;
        u16* Pout = (l == 1) ? PxB : PaB;

        repack_w<<<8192, 256, 0, stream>>>(w, Wx, Wh);
        if (l == 0) transpose_x<<<512, 256, 0, stream>>>(x, PxB);

        for (int t = 0; t < T_STEPS; ++t) {
            if ((t & 1) == 0) {
                // x-part GEMM for timesteps {t, t+1}: N = 4096 (just-in-time,
                // previous chunk's last reader was gates(t-1))
                conv_gemm<128><<<dim3(32, 16), 256, 0, stream>>>(
                    Wx, Pin, Zx, 4096, t, 1);
            }
            if (t > 0) {
                // h-part GEMM on H_{t-1} (plane t-1 of Pout): N = 2048
                conv_gemm<64><<<dim3(32, 16), 256, 0, stream>>>(
                    Wh, Pout, Zh, 2048, t - 1, 0);
            }
            float* outp = (l == 2 && t == T_STEPS - 1) ? (float*)d_out : nullptr;
            gates_kernel<<<256, 256, 0, stream>>>(
                Zx, (t & 1) * 2048, Zh, bias, wci, wcf, wco,
                Cbuf, (t > 0) ? 1 : 0, Pout, t, outp);
        }
    }
}